// Round 1
// baseline (331.769 us; speedup 1.0000x reference)
//
#include <hip/hip_runtime.h>

typedef __attribute__((ext_vector_type(4))) float f32x4;
typedef __attribute__((ext_vector_type(8))) short bf16x8;

#define NEDGE 100000
#define NNODE 10000
#define INV40f 0.15811388300841897f
#define INV120f 0.09128709291752769f

__device__ inline short f2bf(float f) {
    unsigned u = __builtin_bit_cast(unsigned, f);
    u = (u + 0x7fffu + ((u >> 16) & 1u)) >> 16;
    return (short)u;
}

__global__ void zero_f32(float* __restrict__ p, int n) {
    int i = blockIdx.x * 256 + threadIdx.x;
    if (i < n) p[i] = 0.0f;
}

// fc1_w [64k][64n] f32 -> fc1_wt [n][k] bf16 ; fc2_w [64k][1600c] f32 -> fc2_wt [c][k] bf16
__global__ void prep_weights(const float* __restrict__ fc1_w,
                             const float* __restrict__ fc2_w,
                             short* __restrict__ fc1_wt,
                             short* __restrict__ fc2_wt) {
    int t = blockIdx.x * 256 + threadIdx.x;   // 1664*64 threads exactly
    int col = t >> 6, k = t & 63;
    if (col < 64) {
        fc1_wt[col * 64 + k] = f2bf(fc1_w[k * 64 + col]);
    } else {
        int c = col - 64;
        fc2_wt[c * 64 + k] = f2bf(fc2_w[k * 1600 + c]);
    }
}

#define MFMA16(A,B,C) __builtin_amdgcn_mfma_f32_16x16x32_bf16((A),(B),(C),0,0,0)

__global__ __launch_bounds__(256) void edge_fused(
    const float* __restrict__ node_attr,
    const float* __restrict__ edge_attr,
    const float* __restrict__ edge_sh,
    const int*   __restrict__ edge_index,
    const float* __restrict__ fc1_b,
    const float* __restrict__ fc2_b,
    const short* __restrict__ fc1_wt,
    const short* __restrict__ fc2_wt,
    float* __restrict__ sums,
    float* __restrict__ cnt)
{
    __shared__ __align__(16) char h_s[4096];   // h [32][64] bf16, XOR-swizzled
    __shared__ float xbuf[32*57];
    __shared__ float shb[32*4];
    __shared__ float c00s[32*33];   // INV40*s0*x0[u]
    __shared__ float cb1s[32*33];   // INV40*x0[u]
    __shared__ float c10s[32*25];   // INV40*s0*x1[u][i]
    __shared__ float c11s[32*9];    // INV120*a1[u]
    __shared__ float tp0s[32*33];   // out0 accum
    __shared__ float tb1s[32*9];    // b1 accum
    __shared__ float tb2s[32*25];   // b2 accum
    __shared__ int srcs[32];

    const int tid  = threadIdx.x;
    const int lane = tid & 63;
    const int wid  = tid >> 6;
    const int l15  = lane & 15;
    const int lg   = lane >> 4;
    const int e0   = blockIdx.x * 32;

    // ---------- phase 0: gather node rows (dst), edge_sh, src ids ----------
    {
        const int r = tid >> 3, q = tid & 7;
        const int dst = edge_index[NEDGE + e0 + r];
        #pragma unroll
        for (int j = 0; j < 7; j++)
            xbuf[r*57 + q*7 + j] = node_attr[dst*56 + q*7 + j];
        if (tid < 32) {
            srcs[tid] = edge_index[e0 + tid];
            shb[tid*4+0] = edge_sh[(e0+tid)*4+0];
            shb[tid*4+1] = edge_sh[(e0+tid)*4+1];
            shb[tid*4+2] = edge_sh[(e0+tid)*4+2];
            shb[tid*4+3] = edge_sh[(e0+tid)*4+3];
        }
    }
    __syncthreads();

    // ---------- phase 1: coefficient tables + zero tp accumulators ----------
    {
        const int r = tid >> 3, q = tid & 7;
        const float s0 = shb[r*4+0];
        const float sx = shb[r*4+1], sy = shb[r*4+2], sz = shb[r*4+3];
        #pragma unroll
        for (int j = 0; j < 4; j++) {
            const int u = q*4 + j;
            const float x0 = xbuf[r*57 + u];
            c00s[r*33+u] = INV40f * s0 * x0;
            cb1s[r*33+u] = INV40f * x0;
            tp0s[r*33+u] = 0.0f;
        }
        const float xa = xbuf[r*57 + 32 + q*3 + 0];
        const float xb = xbuf[r*57 + 32 + q*3 + 1];
        const float xc = xbuf[r*57 + 32 + q*3 + 2];
        c10s[r*25 + q*3 + 0] = INV40f * s0 * xa;
        c10s[r*25 + q*3 + 1] = INV40f * s0 * xb;
        c10s[r*25 + q*3 + 2] = INV40f * s0 * xc;
        c11s[r*9 + q] = INV120f * (xa*sx + xb*sy + xc*sz);
        tb1s[r*9 + q] = 0.0f;
        tb2s[r*25 + q*3 + 0] = 0.0f;
        tb2s[r*25 + q*3 + 1] = 0.0f;
        tb2s[r*25 + q*3 + 2] = 0.0f;
    }
    __syncthreads();

    // ---------- phase 2: fc1 via MFMA -> h (relu, bf16) into swizzled LDS ----------
    {
        bf16x8 a00, a01, a10, a11;
        {
            const float* p = edge_attr + (size_t)(e0 + l15) * 64 + lg*8;
            #pragma unroll
            for (int i = 0; i < 8; i++) a00[i] = f2bf(p[i]);
            #pragma unroll
            for (int i = 0; i < 8; i++) a01[i] = f2bf(p[32 + i]);
            p = edge_attr + (size_t)(e0 + 16 + l15) * 64 + lg*8;
            #pragma unroll
            for (int i = 0; i < 8; i++) a10[i] = f2bf(p[i]);
            #pragma unroll
            for (int i = 0; i < 8; i++) a11[i] = f2bf(p[32 + i]);
        }
        const bf16x8 b0 = *(const bf16x8*)(fc1_wt + (wid*16 + l15)*64 + lg*8);
        const bf16x8 b1 = *(const bf16x8*)(fc1_wt + (wid*16 + l15)*64 + 32 + lg*8);
        const float bias = fc1_b[wid*16 + l15];
        const int j = wid*16 + l15;
        f32x4 c0 = {0.f,0.f,0.f,0.f}, c1 = {0.f,0.f,0.f,0.f};
        c0 = MFMA16(a00, b0, c0);  c0 = MFMA16(a01, b1, c0);
        c1 = MFMA16(a10, b0, c1);  c1 = MFMA16(a11, b1, c1);
        #pragma unroll
        for (int reg = 0; reg < 4; reg++) {
            int row = lg*4 + reg;
            float v = fmaxf(c0[reg] + bias, 0.0f);
            *(short*)(h_s + ((row*128 + j*2) ^ ((row & 7) << 4))) = f2bf(v);
            row += 16;
            v = fmaxf(c1[reg] + bias, 0.0f);
            *(short*)(h_s + ((row*128 + j*2) ^ ((row & 7) << 4))) = f2bf(v);
        }
    }
    __syncthreads();

    // ---------- phase 3: load H A-fragments (reused across all 25 N-frags) ----------
    bf16x8 h00, h01, h10, h11;
    {
        int row = l15;
        h00 = *(const bf16x8*)(h_s + ((row*128 +  0 + lg*16) ^ ((row & 7) << 4)));
        h01 = *(const bf16x8*)(h_s + ((row*128 + 64 + lg*16) ^ ((row & 7) << 4)));
        row = 16 + l15;
        h10 = *(const bf16x8*)(h_s + ((row*128 +  0 + lg*16) ^ ((row & 7) << 4)));
        h11 = *(const bf16x8*)(h_s + ((row*128 + 64 + lg*16) ^ ((row & 7) << 4)));
    }

    // ---------- phase 4: fc2 MFMA + fused tensor-product consume ----------
    float acc0[2][4] = {{0,0,0,0},{0,0,0,0}};
    float ab1 [2][4] = {{0,0,0,0},{0,0,0,0}};
    float ab2 [2][4][3] = {};
    const short* pB0 = fc2_wt + l15*64 + lg*8;
    const int lg4 = lg*4;

    // region w00: nf = wid + 4*ii, ii in [0,16)   -> out0, u = (wid>>1)+2*ii, slot = wid&1
    #pragma unroll 4
    for (int ii = 0; ii < 16; ii++) {
        const int nf = wid + 4*ii;
        const bf16x8 b0 = *(const bf16x8*)(pB0 + nf*1024);
        const bf16x8 b1 = *(const bf16x8*)(pB0 + nf*1024 + 32);
        const float bias = fc2_b[nf*16 + l15];
        f32x4 c0 = {0.f,0.f,0.f,0.f}, c1 = {0.f,0.f,0.f,0.f};
        c0 = MFMA16(h00, b0, c0);  c0 = MFMA16(h01, b1, c0);
        c1 = MFMA16(h10, b0, c1);  c1 = MFMA16(h11, b1, c1);
        const int u = (wid >> 1) + 2*ii;
        #pragma unroll
        for (int reg = 0; reg < 4; reg++) {
            acc0[0][reg] += c00s[(lg4+reg)*33 + u]      * (c0[reg] + bias);
            acc0[1][reg] += c00s[(16+lg4+reg)*33 + u]   * (c1[reg] + bias);
        }
    }
    // region w01: nf = wid + 64 + 4*ii, ii in [0,4) -> b1, u = 2*(wid+4*ii) + (l15>>3)
    #pragma unroll
    for (int ii = 0; ii < 4; ii++) {
        const int nf = wid + 64 + 4*ii;
        const bf16x8 b0 = *(const bf16x8*)(pB0 + nf*1024);
        const bf16x8 b1 = *(const bf16x8*)(pB0 + nf*1024 + 32);
        const float bias = fc2_b[nf*16 + l15];
        f32x4 c0 = {0.f,0.f,0.f,0.f}, c1 = {0.f,0.f,0.f,0.f};
        c0 = MFMA16(h00, b0, c0);  c0 = MFMA16(h01, b1, c0);
        c1 = MFMA16(h10, b0, c1);  c1 = MFMA16(h11, b1, c1);
        const int u = 2*(wid + 4*ii) + (l15 >> 3);
        #pragma unroll
        for (int reg = 0; reg < 4; reg++) {
            ab1[0][reg] += cb1s[(lg4+reg)*33 + u]    * (c0[reg] + bias);
            ab1[1][reg] += cb1s[(16+lg4+reg)*33 + u] * (c1[reg] + bias);
        }
    }
    // region w10: nf = wid + 80 -> b2, u = 2*wid + (l15>>3)
    {
        const int nf = wid + 80;
        const bf16x8 b0 = *(const bf16x8*)(pB0 + nf*1024);
        const bf16x8 b1 = *(const bf16x8*)(pB0 + nf*1024 + 32);
        const float bias = fc2_b[nf*16 + l15];
        f32x4 c0 = {0.f,0.f,0.f,0.f}, c1 = {0.f,0.f,0.f,0.f};
        c0 = MFMA16(h00, b0, c0);  c0 = MFMA16(h01, b1, c0);
        c1 = MFMA16(h10, b0, c1);  c1 = MFMA16(h11, b1, c1);
        const int u = 2*wid + (l15 >> 3);
        #pragma unroll
        for (int reg = 0; reg < 4; reg++) {
            const float v0 = c0[reg] + bias, v1 = c1[reg] + bias;
            #pragma unroll
            for (int i = 0; i < 3; i++) {
                ab2[0][reg][i] += c10s[(lg4+reg)*25 + u*3 + i]    * v0;
                ab2[1][reg][i] += c10s[(16+lg4+reg)*25 + u*3 + i] * v1;
            }
        }
    }
    // region w11: nf = wid + 84 + 4*ii, ii in [0,4) -> out0, u = (wid>>1)+2*ii
    #pragma unroll
    for (int ii = 0; ii < 4; ii++) {
        const int nf = wid + 84 + 4*ii;
        const bf16x8 b0 = *(const bf16x8*)(pB0 + nf*1024);
        const bf16x8 b1 = *(const bf16x8*)(pB0 + nf*1024 + 32);
        const float bias = fc2_b[nf*16 + l15];
        f32x4 c0 = {0.f,0.f,0.f,0.f}, c1 = {0.f,0.f,0.f,0.f};
        c0 = MFMA16(h00, b0, c0);  c0 = MFMA16(h01, b1, c0);
        c1 = MFMA16(h10, b0, c1);  c1 = MFMA16(h11, b1, c1);
        const int u = (wid >> 1) + 2*ii;
        #pragma unroll
        for (int reg = 0; reg < 4; reg++) {
            acc0[0][reg] += c11s[(lg4+reg)*9 + u]    * (c0[reg] + bias);
            acc0[1][reg] += c11s[(16+lg4+reg)*9 + u] * (c1[reg] + bias);
        }
    }

    // ---------- reduce partials into LDS tp arrays ----------
    {
        const int slot16 = (wid & 1) << 4;
        #pragma unroll
        for (int mf = 0; mf < 2; mf++) {
            #pragma unroll
            for (int reg = 0; reg < 4; reg++) {
                const int r = mf*16 + lg4 + reg;
                atomicAdd(&tp0s[r*33 + slot16 + l15], acc0[mf][reg]);
                atomicAdd(&tb1s[r*9  + (l15 & 7)],    ab1[mf][reg]);
                atomicAdd(&tb2s[r*25 + (l15&7)*3 + 0], ab2[mf][reg][0]);
                atomicAdd(&tb2s[r*25 + (l15&7)*3 + 1], ab2[mf][reg][1]);
                atomicAdd(&tb2s[r*25 + (l15&7)*3 + 2], ab2[mf][reg][2]);
            }
        }
    }
    __syncthreads();

    // ---------- scatter: atomicAdd into node sums ----------
    #pragma unroll
    for (int j = 0; j < 7; j++) {
        const int idx = tid*7 + j;          // 0..1791 = 32 edges * 56
        const int r = idx / 56;
        const int c = idx - r*56;
        float val;
        if (c < 32) {
            val = tp0s[r*33 + c];
        } else {
            const int d = c - 32;
            const int w = d / 3, i = d - w*3;
            val = shb[r*4 + 1 + i] * tb1s[r*9 + w] + tb2s[r*25 + d];
        }
        unsafeAtomicAdd(&sums[(size_t)srcs[r]*56 + c], val);
    }
    if (tid < 32) unsafeAtomicAdd(&cnt[srcs[tid]], 1.0f);
}

// out_pre = sums/max(cnt,1) + node_attr ; partial BN stats
__global__ __launch_bounds__(256) void node_pre(
    const float* __restrict__ sums, const float* __restrict__ cnt,
    const float* __restrict__ node_attr, float* __restrict__ out,
    float* __restrict__ stats)
{
    __shared__ float part[72];
    const int tid = threadIdx.x;
    if (tid < 72) part[tid] = 0.0f;
    __syncthreads();
    const int c = tid & 63, nsub = tid >> 6;
    if (c < 56) {
        #pragma unroll
        for (int rep = 0; rep < 8; rep++) {
            const int n = blockIdx.x*32 + nsub + rep*4;
            if (n < NNODE) {
                const float cc = cnt[n];
                const float inv = 1.0f / fmaxf(cc, 1.0f);
                const float val = sums[(size_t)n*56 + c] * inv + node_attr[(size_t)n*56 + c];
                out[(size_t)n*56 + c] = val;
                if (c < 32) {
                    atomicAdd(&part[c], val);
                    atomicAdd(&part[32 + c], val*val);
                } else {
                    atomicAdd(&part[64 + (c-32)/3], val*val);
                }
            }
        }
    }
    __syncthreads();
    if (tid < 72) unsafeAtomicAdd(&stats[tid], part[tid]);
}

__global__ __launch_bounds__(256) void node_norm(
    float* __restrict__ out, const float* __restrict__ stats,
    const float* __restrict__ g0, const float* __restrict__ b0,
    const float* __restrict__ g1)
{
    const int id = blockIdx.x*256 + threadIdx.x;
    if (id >= NNODE*56) return;
    const int c = id % 56;
    float val = out[id];
    if (c < 32) {
        const float m   = stats[c]      * (1.0f / NNODE);
        const float ex2 = stats[32 + c] * (1.0f / NNODE);
        const float var = ex2 - m*m;
        val = (val - m) * rsqrtf(var + 1e-5f) * g0[c] + b0[c];
    } else {
        const int v = (c - 32) / 3;
        const float vn = stats[64 + v] * (1.0f / (3.0f * NNODE));
        val = val * rsqrtf(vn + 1e-5f) * g1[v];
    }
    out[id] = val;
}

extern "C" void kernel_launch(void* const* d_in, const int* in_sizes, int n_in,
                              void* d_out, int out_size, void* d_ws, size_t ws_size,
                              hipStream_t stream) {
    const float* node_attr = (const float*)d_in[0];
    const float* edge_attr = (const float*)d_in[1];
    const float* edge_sh   = (const float*)d_in[2];
    const int*   edge_index= (const int*)  d_in[3];
    const float* fc1_w     = (const float*)d_in[4];
    const float* fc1_b     = (const float*)d_in[5];
    const float* fc2_w     = (const float*)d_in[6];
    const float* fc2_b     = (const float*)d_in[7];
    const float* g0        = (const float*)d_in[8];
    const float* b0        = (const float*)d_in[9];
    const float* g1        = (const float*)d_in[10];
    float* out = (float*)d_out;

    char* ws = (char*)d_ws;
    float* sums  = (float*)ws;                        // 560000 f32
    float* cnt   = sums + 560000;                     // 10000 f32
    float* stats = cnt + 10000;                       // 72 f32
    short* fc1_wt = (short*)(ws + 2280288);           // 64*64 bf16 (16B aligned)
    short* fc2_wt = (short*)(ws + 2288480);           // 1600*64 bf16 (16B aligned)

    zero_f32<<<2227, 256, 0, stream>>>(sums, 570072);
    prep_weights<<<416, 256, 0, stream>>>(fc1_w, fc2_w, fc1_wt, fc2_wt);
    edge_fused<<<3125, 256, 0, stream>>>(node_attr, edge_attr, edge_sh, edge_index,
                                         fc1_b, fc2_b, fc1_wt, fc2_wt, sums, cnt);
    node_pre<<<313, 256, 0, stream>>>(sums, cnt, node_attr, out, stats);
    node_norm<<<2188, 256, 0, stream>>>(out, stats, g0, b0, g1);
}